// Round 1
// baseline (447.776 us; speedup 1.0000x reference)
//
#include <hip/hip_runtime.h>
#include <stdint.h>

#define V 8192
#define C 128
#define KS 8
#define KCH (V / KS)   // 1024
#define BK 64
#define NI (KCH / BK)  // 16 k-tiles per chunk

typedef __attribute__((ext_vector_type(8))) short short8;
typedef __attribute__((ext_vector_type(4))) float floatx4;

static __device__ __forceinline__ unsigned short f2bf(float f) {
    unsigned u = __float_as_uint(f);
    u += 0x7FFF + ((u >> 16) & 1);   // RNE
    return (unsigned short)(u >> 16);
}

// async global->LDS, 16B per lane; LDS dest is wave-uniform base + lane*16
static __device__ __forceinline__ void gload16(const void* g, void* l) {
    __builtin_amdgcn_global_load_lds(
        (const __attribute__((address_space(1))) void*)g,
        (__attribute__((address_space(3))) void*)l, 16, 0, 0);
}
#define SWAIT(s) asm volatile("s_waitcnt " s ::: "memory")

// ---------------------------------------------------------------- prep
// XMT[c][k] = bf16(x[k][c] * mass[k]); 64x64 LDS tiled transpose
__global__ __launch_bounds__(256) void prep_xmt(const float* __restrict__ x,
                                                const float* __restrict__ mass,
                                                unsigned short* __restrict__ XMT) {
    __shared__ float tile[64][65];
    const int k0 = blockIdx.x * 64;
    const int c0 = blockIdx.y * 64;
    const int t = threadIdx.x;
#pragma unroll
    for (int p = 0; p < 16; ++p) {
        int idx = p * 256 + t;
        int kk = idx >> 6, cc = idx & 63;
        tile[kk][cc] = x[(size_t)(k0 + kk) * C + (c0 + cc)] * mass[k0 + kk];
    }
    __syncthreads();
#pragma unroll
    for (int p = 0; p < 16; ++p) {
        int idx = p * 256 + t;
        int cc = idx >> 6, kk = idx & 63;
        XMT[(size_t)(c0 + cc) * V + (k0 + kk)] = f2bf(tile[kk][cc]);
    }
}

// Shared MFMA inner step (reads swizzled LDS, 32 MFMA/wave per tile)
#define MFMA_BODY(pA, pB)                                                           \
    {                                                                               \
        _Pragma("unroll")                                                           \
        for (int kk = 0; kk < BK; kk += 32) {                                       \
            short8 af[4], bfv[4];                                                   \
            _Pragma("unroll")                                                       \
            for (int mi = 0; mi < 4; ++mi) {                                        \
                const int m = wm + mi * 16 + l15;                                   \
                const int cpos = ((kk >> 3) + q) ^ (m & 7);                         \
                af[mi] = *(const short8*)&pA[m * BK + 8 * cpos];                    \
            }                                                                       \
            _Pragma("unroll")                                                       \
            for (int ni = 0; ni < 4; ++ni) {                                        \
                const int n = wn + ni * 16 + l15;                                   \
                const int cpos = ((kk >> 3) + q) ^ (n & 7);                         \
                bfv[ni] = *(const short8*)&pB[n * BK + 8 * cpos];                   \
            }                                                                       \
            _Pragma("unroll")                                                       \
            for (int mi = 0; mi < 4; ++mi)                                          \
                _Pragma("unroll")                                                   \
                for (int ni = 0; ni < 4; ++ni)                                      \
                    acc[mi][ni] = __builtin_amdgcn_mfma_f32_16x16x32_bf16(          \
                        af[mi], bfv[ni], acc[mi][ni], 0, 0, 0);                     \
        }                                                                           \
    }

// ---------------------------------------------------------------- GEMM1
// P1[ks][c][j] = sum_{v in chunk ks} XMT[c][v] * E[v][j]
// A = XMT bf16 via global_load_lds (swizzle folded into per-lane global addr).
// B = fp32 E, transpose+convert fused; loads issued pre-MFMA, consumed post-MFMA.
// LDS double-buffered, one raw barrier per k-tile (no vmcnt(0) drain mid-pipe).
__global__ __launch_bounds__(256, 2) void gemm1_fused(const unsigned short* __restrict__ XMT,
                                                      const float* __restrict__ E,
                                                      float* __restrict__ P1) {
    __shared__ __align__(16) unsigned short ldsA[2][128 * BK];
    __shared__ __align__(16) unsigned short ldsB[2][128 * BK];
    const int bx = blockIdx.x;
    const int ks = bx & (KS - 1);
    const int n0 = (bx >> 3) * 128;
    const int kb = ks * KCH;
    const int t = threadIdx.x;
    const int w = t >> 6, lane = t & 63, q = lane >> 4, l15 = lane & 15;
    const int wm = (w & 1) * 64, wn = (w >> 1) * 64;
    // A staging (gload_lds): lane l of call (i,w) fills LDS row r=i*32+w*8+(l>>3),
    // 16B slot s=l&7; source chunk = s ^ (r&7)  (LDS layout identical to MFMA_BODY's)
    const int lr = lane >> 3;
    const int lch = (lane & 7) ^ lr;
    // B staging (E transpose repack): 8 rows (v) x 4 cols (j) per thread
    const int jg = (lane & 7) | (w << 3);  // j-chunk 0..31 (4 cols each)
    const int vq = lane >> 3;              // v-octet 0..7

    floatx4 acc[4][4] = {};
    float4 ereg[8];

    // ---- prologue: stage tile 0 into buf 0
    {
        const int k0 = kb;
#pragma unroll
        for (int i = 0; i < 4; ++i)
            gload16(&XMT[(size_t)(i * 32 + w * 8 + lr) * V + k0 + 8 * lch],
                    &ldsA[0][i * 2048 + w * 512]);
#pragma unroll
        for (int rr = 0; rr < 8; ++rr)
            ereg[rr] = *(const float4*)&E[(size_t)(k0 + vq * 8 + rr) * V + n0 + jg * 4];
        const float* lf = (const float*)ereg;
#pragma unroll
        for (int jj = 0; jj < 4; ++jj) {
            const int j = jg * 4 + jj;
            short8 b;
#pragma unroll
            for (int rr = 0; rr < 8; ++rr) b[rr] = (short)f2bf(lf[rr * 4 + jj]);
            *(short8*)&ldsB[0][j * BK + (vq ^ (j & 7)) * 8] = b;
        }
        SWAIT("vmcnt(0) lgkmcnt(0)");
        __builtin_amdgcn_s_barrier();
        __builtin_amdgcn_sched_barrier(0);
    }

    int cur = 0;
    for (int tt = 0; tt < NI; ++tt) {
        const bool pf = (tt + 1 < NI);
        if (pf) {
            const int kn = kb + (tt + 1) * BK;
#pragma unroll
            for (int i = 0; i < 4; ++i)
                gload16(&XMT[(size_t)(i * 32 + w * 8 + lr) * V + kn + 8 * lch],
                        &ldsA[cur ^ 1][i * 2048 + w * 512]);
#pragma unroll
            for (int rr = 0; rr < 8; ++rr)
                ereg[rr] = *(const float4*)&E[(size_t)(kn + vq * 8 + rr) * V + n0 + jg * 4];
        }
        __builtin_amdgcn_sched_barrier(0);
        {
            const unsigned short* pA = ldsA[cur];
            const unsigned short* pB = ldsB[cur];
            __builtin_amdgcn_s_setprio(1);
            MFMA_BODY(pA, pB);
            __builtin_amdgcn_s_setprio(0);
        }
        __builtin_amdgcn_sched_barrier(0);
        if (pf) {
            // e-loads drain here (compiler-counted vmcnt) — after a full MFMA phase
            const float* lf = (const float*)ereg;
#pragma unroll
            for (int jj = 0; jj < 4; ++jj) {
                const int j = jg * 4 + jj;
                short8 b;
#pragma unroll
                for (int rr = 0; rr < 8; ++rr) b[rr] = (short)f2bf(lf[rr * 4 + jj]);
                *(short8*)&ldsB[cur ^ 1][j * BK + (vq ^ (j & 7)) * 8] = b;
            }
        }
        SWAIT("vmcnt(0) lgkmcnt(0)");
        __builtin_amdgcn_s_barrier();
        __builtin_amdgcn_sched_barrier(0);
        cur ^= 1;
    }

    float* Pks = P1 + (size_t)ks * C * V;
#pragma unroll
    for (int mi = 0; mi < 4; ++mi) {
        int mrow = wm + mi * 16 + q * 4;
#pragma unroll
        for (int ni = 0; ni < 4; ++ni) {
            int n = n0 + wn + ni * 16 + l15;
#pragma unroll
            for (int r = 0; r < 4; ++r)
                Pks[(size_t)(mrow + r) * V + n] = acc[mi][ni][r];
        }
    }
}

// ---------------------------------------------------------------- GEMM2
// P2[ks][i][c] = sum_{j in chunk ks} E[i][j] * YT[c][j]
// A = fp32 E rows (reg + convert, post-MFMA consume). B = YT bf16 via gload_lds.
__global__ __launch_bounds__(256, 2) void gemm2_fused(const float* __restrict__ E,
                                                      const unsigned short* __restrict__ YT,
                                                      float* __restrict__ P2) {
    __shared__ __align__(16) unsigned short ldsA[2][128 * BK];
    __shared__ __align__(16) unsigned short ldsB[2][128 * BK];
    const int bx = blockIdx.x;
    const int ks = bx & (KS - 1);
    const int m0 = (bx >> 3) * 128;
    const int kb = ks * KCH;
    const int t = threadIdx.x;
    const int w = t >> 6, lane = t & 63, q = lane >> 4, l15 = lane & 15;
    const int wm = (w & 1) * 64, wn = (w >> 1) * 64;
    // B staging (gload_lds from YT) — same swizzled-source map as GEMM1's A
    const int lr = lane >> 3;
    const int lch = (lane & 7) ^ lr;
    // A staging: 16 lanes cover one full 256B fp32 row segment; rows ar+16u
    const int ach = t & 15;
    const int ar  = t >> 4;

    floatx4 acc[4][4] = {};
    float4 ereg[8];

    // ---- prologue: stage tile 0
    {
        const int k0 = kb;
#pragma unroll
        for (int i = 0; i < 4; ++i)
            gload16(&YT[(size_t)(i * 32 + w * 8 + lr) * V + k0 + 8 * lch],
                    &ldsB[0][i * 2048 + w * 512]);
#pragma unroll
        for (int u = 0; u < 8; ++u)
            ereg[u] = *(const float4*)&E[(size_t)(m0 + ar + 16 * u) * V + k0 + ach * 4];
        const float* lf = (const float*)ereg;
#pragma unroll
        for (int u = 0; u < 8; ++u) {
            const int row = ar + 16 * u;
            ushort4 av;
            av.x = f2bf(lf[u * 4 + 0]); av.y = f2bf(lf[u * 4 + 1]);
            av.z = f2bf(lf[u * 4 + 2]); av.w = f2bf(lf[u * 4 + 3]);
            *(ushort4*)&ldsA[0][row * BK + ((ach >> 1) ^ (row & 7)) * 8 + (ach & 1) * 4] = av;
        }
        SWAIT("vmcnt(0) lgkmcnt(0)");
        __builtin_amdgcn_s_barrier();
        __builtin_amdgcn_sched_barrier(0);
    }

    int cur = 0;
    for (int tt = 0; tt < NI; ++tt) {
        const bool pf = (tt + 1 < NI);
        if (pf) {
            const int kn = kb + (tt + 1) * BK;
#pragma unroll
            for (int i = 0; i < 4; ++i)
                gload16(&YT[(size_t)(i * 32 + w * 8 + lr) * V + kn + 8 * lch],
                        &ldsB[cur ^ 1][i * 2048 + w * 512]);
#pragma unroll
            for (int u = 0; u < 8; ++u)
                ereg[u] = *(const float4*)&E[(size_t)(m0 + ar + 16 * u) * V + kn + ach * 4];
        }
        __builtin_amdgcn_sched_barrier(0);
        {
            const unsigned short* pA = ldsA[cur];
            const unsigned short* pB = ldsB[cur];
            __builtin_amdgcn_s_setprio(1);
            MFMA_BODY(pA, pB);
            __builtin_amdgcn_s_setprio(0);
        }
        __builtin_amdgcn_sched_barrier(0);
        if (pf) {
            const float* lf = (const float*)ereg;
#pragma unroll
            for (int u = 0; u < 8; ++u) {
                const int row = ar + 16 * u;
                ushort4 av;
                av.x = f2bf(lf[u * 4 + 0]); av.y = f2bf(lf[u * 4 + 1]);
                av.z = f2bf(lf[u * 4 + 2]); av.w = f2bf(lf[u * 4 + 3]);
                *(ushort4*)&ldsA[cur ^ 1][row * BK + ((ach >> 1) ^ (row & 7)) * 8 + (ach & 1) * 4] = av;
            }
        }
        SWAIT("vmcnt(0) lgkmcnt(0)");
        __builtin_amdgcn_s_barrier();
        __builtin_amdgcn_sched_barrier(0);
        cur ^= 1;
    }

    float* Pks = P2 + (size_t)ks * V * C;
#pragma unroll
    for (int mi = 0; mi < 4; ++mi) {
        int mrow = m0 + wm + mi * 16 + q * 4;
#pragma unroll
        for (int ni = 0; ni < 4; ++ni) {
            int n = wn + ni * 16 + l15;
#pragma unroll
            for (int r = 0; r < 4; ++r)
                Pks[(size_t)(mrow + r) * C + n] = acc[mi][ni][r];
        }
    }
}

// ---------------------------------------------------------------- reductions
__global__ __launch_bounds__(256) void red1(const float* __restrict__ P1,
                                            const float* __restrict__ ev0,
                                            const float* __restrict__ ev1,
                                            const float* __restrict__ dt,
                                            unsigned short* __restrict__ YT) {
    int id = blockIdx.x * 256 + threadIdx.x;
    int c = id >> 10;
    int j0 = (id & 1023) * 8;
    float s[8] = {};
#pragma unroll
    for (int ks = 0; ks < KS; ++ks) {
        const float* row = &P1[((size_t)ks * C + c) * V + j0];
        float4 a = *(const float4*)row;
        float4 b = *(const float4*)(row + 4);
        s[0] += a.x; s[1] += a.y; s[2] += a.z; s[3] += a.w;
        s[4] += b.x; s[5] += b.y; s[6] += b.z; s[7] += b.w;
    }
    float t0 = dt[c], t1 = dt[C + c];
    float a0 = ev0[j0 >> 7] * t0;
    short8 yv;
#pragma unroll
    for (int jj = 0; jj < 8; ++jj) {
        float coef = __expf(-(a0 + ev1[(j0 + jj) & 127] * t1));
        yv[jj] = (short)f2bf(s[jj] * coef);
    }
    *(short8*)&YT[(size_t)c * V + j0] = yv;
}

__global__ __launch_bounds__(256) void red2(const float* __restrict__ P2,
                                            float* __restrict__ out) {
    int id = blockIdx.x * 256 + threadIdx.x;
    size_t off = (size_t)id * 4;
    float4 s = {0.f, 0.f, 0.f, 0.f};
#pragma unroll
    for (int ks = 0; ks < KS; ++ks) {
        float4 v = *(const float4*)&P2[(size_t)ks * V * C + off];
        s.x += v.x; s.y += v.y; s.z += v.z; s.w += v.w;
    }
    *(float4*)&out[off] = s;
}

// ---------------------------------------------------------------- launch
extern "C" void kernel_launch(void* const* d_in, const int* in_sizes, int n_in,
                              void* d_out, int out_size, void* d_ws, size_t ws_size,
                              hipStream_t stream) {
    const float* x    = (const float*)d_in[0];
    const float* mass = (const float*)d_in[3];
    const float* ev0  = (const float*)d_in[4];
    const float* ev1  = (const float*)d_in[5];
    const float* E    = (const float*)d_in[6];
    const float* dt   = (const float*)d_in[7];
    float* out = (float*)d_out;

    // ws: XMT (2 MB) | YT (2 MB) | P (32 MB, reused by both GEMMs)
    unsigned short* XMT = (unsigned short*)d_ws;
    unsigned short* YT  = XMT + (size_t)V * C;
    float* P = (float*)(YT + (size_t)V * C);

    prep_xmt<<<dim3(V / 64, C / 64), 256, 0, stream>>>(x, mass, XMT);
    gemm1_fused<<<(V / 128) * KS, 256, 0, stream>>>(XMT, E, P);
    red1<<<(C * V / 8) / 256, 256, 0, stream>>>(P, ev0, ev1, dt, YT);
    gemm2_fused<<<(V / 128) * KS, 256, 0, stream>>>(E, YT, P);
    red2<<<(V * C / 4) / 256, 256, 0, stream>>>(P, out);
}